// Round 5
// baseline (415.991 us; speedup 1.0000x reference)
//
#include <hip/hip_runtime.h>
#include <hip/hip_bf16.h>
#include <hip/hip_cooperative_groups.h>
#include <stdint.h>

namespace cg = cooperative_groups;

#define NN 4096
#define NF 128

using f32x4  = __attribute__((ext_vector_type(4))) float;
using f32x16 = __attribute__((ext_vector_type(16))) float;
using bf16x8 = __attribute__((ext_vector_type(8))) __bf16;
using u16x8  = __attribute__((ext_vector_type(8))) uint16_t;
using i32x4  = __attribute__((ext_vector_type(4))) int;
using i32x8  = __attribute__((ext_vector_type(8))) int;

__device__ __forceinline__ uint16_t f2b(float f) {
    union { float f; uint32_t u; } v; v.f = f;
    uint32_t r = v.u + 0x7FFFu + ((v.u >> 16) & 1u);
    return (uint16_t)(r >> 16);
}

__device__ __forceinline__ uint32_t pk_fp8x4(float a, float b, float c, float d) {
    int p = __builtin_amdgcn_cvt_pk_fp8_f32(a, b, 0, false);
    p = __builtin_amdgcn_cvt_pk_fp8_f32(c, d, p, true);
    return (uint32_t)p;
}

__device__ __forceinline__ void gld_lds16(const void* g, void* l) {
    __builtin_amdgcn_global_load_lds(
        (const __attribute__((address_space(1))) uint32_t*)g,
        (__attribute__((address_space(3))) uint32_t*)l,
        16, 0, 0);
}

// ---------------------------------------------------------------------------
// Kernel 1: XW = X@W, s_col = XW@a[:128], s_row = XW@a[128:], XWT bf16
// ---------------------------------------------------------------------------
__global__ void xw_kernel(const float* __restrict__ X, const float* __restrict__ W,
                          const float* __restrict__ a,
                          uint16_t* __restrict__ XWT,
                          float* __restrict__ s_col, float* __restrict__ s_row) {
    __shared__ float xs[NF];
    __shared__ float red[4];
    const int i = blockIdx.x, f = threadIdx.x;
    xs[f] = X[i * NF + f];
    __syncthreads();
    float acc = 0.f;
    #pragma unroll 8
    for (int k = 0; k < NF; ++k) acc += xs[k] * W[k * NF + f];
    XWT[(size_t)f * NN + i] = f2b(acc);
    float sc = acc * a[f];
    float sr = acc * a[NF + f];
    #pragma unroll
    for (int off = 32; off; off >>= 1) {
        sc += __shfl_down(sc, off);
        sr += __shfl_down(sr, off);
    }
    if ((f & 63) == 0) { red[f >> 6] = sc; red[2 + (f >> 6)] = sr; }
    __syncthreads();
    if (f == 0) {
        s_col[i] = red[0] + red[1];
        s_row[i] = red[2] + red[3];
    }
}

// ---------------------------------------------------------------------------
// Kernel 2: A fp32 -> fp8-e4m3 only (bf16 copy no longer needed)
// ---------------------------------------------------------------------------
__global__ void conv8_kernel(const float* __restrict__ in, uint32_t* __restrict__ o8) {
    int idx = blockIdx.x * blockDim.x + threadIdx.x;
    float4 v = ((const float4*)in)[idx];
    o8[idx] = pk_fp8x4(v.x, v.y, v.z, v.w);
}

// ---------------------------------------------------------------------------
// Kernel 3: denT8[j][k] = fp8(exp(leaky_relu(s_row[k] + s_col[j])))
// ---------------------------------------------------------------------------
__global__ void denT_kernel(const float* __restrict__ s_row, const float* __restrict__ s_col,
                            uint32_t* __restrict__ denT8) {
    int idx = blockIdx.x * blockDim.x + threadIdx.x;
    int j = idx >> 10;
    int k = (idx & 1023) << 2;
    float sc = s_col[j];
    float4 sr = *(const float4*)(s_row + k);
    float z0 = sc + sr.x; z0 = z0 > 0.f ? z0 : 0.01f * z0;
    float z1 = sc + sr.y; z1 = z1 > 0.f ? z1 : 0.01f * z1;
    float z2 = sc + sr.z; z2 = z2 > 0.f ? z2 : 0.01f * z2;
    float z3 = sc + sr.w; z3 = z3 > 0.f ? z3 : 0.01f * z3;
    denT8[idx] = pk_fp8x4(__expf(z0), __expf(z1), __expf(z2), __expf(z3));
}

// ---------------------------------------------------------------------------
// Kernel 4 (R3 version): num = A@den via MX-FP8 mfma_scale 32x32x64.
// One-pass LDS epilogue (VGPR 88); att = bf16(den/num).
// ---------------------------------------------------------------------------
__global__ __launch_bounds__(256) void gemm_att_kernel(
    const uint8_t* __restrict__ Ab8, const uint8_t* __restrict__ Bt8,
    const float* __restrict__ s_row, const float* __restrict__ s_col,
    uint16_t* __restrict__ att) {
    __shared__ __align__(16) char smem[128 * 272];
    char* As = smem;
    char* Bs = smem + 8192;
    const int bm0 = blockIdx.y * 128, bn0 = blockIdx.x * 128;

    const int tid  = threadIdx.x;
    const int lane = tid & 63;
    const int wid  = tid >> 6;
    const int wy   = wid >> 1, wx = wid & 1;
    const int m    = lane & 31, h = lane >> 5;

    const int sr_ = tid >> 2;
    const int scb = (((tid & 3) ^ ((sr_ >> 1) & 3)) << 4);

    f32x16 acc[2][2];
    #pragma unroll
    for (int mi = 0; mi < 2; ++mi)
        #pragma unroll
        for (int ni = 0; ni < 2; ++ni)
            #pragma unroll
            for (int r = 0; r < 16; ++r) acc[mi][ni][r] = 0.f;

    const int sw = (m >> 1) & 3;
    const int c0 = ((2 * h) ^ sw) << 4;
    const int c1 = ((2 * h + 1) ^ sw) << 4;

    for (int k0 = 0; k0 < NN; k0 += 64) {
        __syncthreads();
        gld_lds16(Ab8 + (size_t)(bm0 +      sr_) * NN + k0 + scb, As +        tid * 16);
        gld_lds16(Ab8 + (size_t)(bm0 + 64 + sr_) * NN + k0 + scb, As + 4096 + tid * 16);
        gld_lds16(Bt8 + (size_t)(bn0 +      sr_) * NN + k0 + scb, Bs +        tid * 16);
        gld_lds16(Bt8 + (size_t)(bn0 + 64 + sr_) * NN + k0 + scb, Bs + 4096 + tid * 16);
        __syncthreads();
        i32x8 af[2], bf[2];
        #pragma unroll
        for (int mi = 0; mi < 2; ++mi) {
            const char* p = As + (wy * 64 + mi * 32 + m) * 64;
            i32x4 lo = *(const i32x4*)(p + c0);
            i32x4 hi = *(const i32x4*)(p + c1);
            af[mi] = (i32x8){lo[0], lo[1], lo[2], lo[3], hi[0], hi[1], hi[2], hi[3]};
        }
        #pragma unroll
        for (int ni = 0; ni < 2; ++ni) {
            const char* p = Bs + (wx * 64 + ni * 32 + m) * 64;
            i32x4 lo = *(const i32x4*)(p + c0);
            i32x4 hi = *(const i32x4*)(p + c1);
            bf[ni] = (i32x8){lo[0], lo[1], lo[2], lo[3], hi[0], hi[1], hi[2], hi[3]};
        }
        #pragma unroll
        for (int mi = 0; mi < 2; ++mi)
            #pragma unroll
            for (int ni = 0; ni < 2; ++ni)
                acc[mi][ni] = __builtin_amdgcn_mfma_scale_f32_32x32x64_f8f6f4(
                    af[mi], bf[ni], acc[mi][ni], 0, 0,
                    0, 0x7F7F7F7F, 0, 0x7F7F7F7F);
    }

    __syncthreads();
    uint16_t* smem16 = (uint16_t*)smem;

    #pragma unroll
    for (int ni = 0; ni < 2; ++ni) {
        const int jl = wx * 64 + ni * 32 + m;
        const float scj = s_col[bn0 + jl];
        #pragma unroll
        for (int mi = 0; mi < 2; ++mi) {
            #pragma unroll
            for (int reg = 0; reg < 16; ++reg) {
                const int row = (reg & 3) + 8 * (reg >> 2) + 4 * h;
                const int il = wy * 64 + mi * 32 + row;
                float z = s_row[bm0 + il] + scj;
                z = z > 0.f ? z : 0.01f * z;
                const float den = __expf(z);
                const float num = acc[mi][ni][reg];
                float v = den * __builtin_amdgcn_rcpf(num);
                v = (num != 0.f) ? v : 0.f;
                smem16[il * 136 + jl] = f2b(v);
            }
        }
    }
    __syncthreads();
    {
        const int row = tid >> 1, half = tid & 1;
        const u16x8* src = (const u16x8*)(smem16 + row * 136 + half * 64);
        u16x8* dst = (u16x8*)(att + (size_t)(bm0 + row) * NN + bn0 + half * 64);
        #pragma unroll
        for (int c = 0; c < 8; ++c) dst[c] = src[c];
    }
}

// ---------------------------------------------------------------------------
// Kernel 5 (cooperative): replaces splitk x2 + reduce x2.
// 256 blocks x 256 threads, 1 block/CU. Each block owns 16 output rows.
// Phase 1: M1 = att @ XW  (B^T = XWT[j][k]) -> writes M1T[j][i] bf16 via LDS
//          transpose.
// grid.sync()
// Phase 2: H = A @ M1     (B^T = M1T), A fp32 converted to bf16 in-register.
// ---------------------------------------------------------------------------
__global__ __launch_bounds__(256) void tail_kernel(
    const uint16_t* __restrict__ att, const uint16_t* __restrict__ XWT,
    const float* __restrict__ A, uint16_t* __restrict__ M1T,
    float* __restrict__ H) {
    __shared__ __align__(16) char smem[16384];
    char* Asm = smem;              // phase1: 16x64B bf16; phase2: 16x128B fp32
    char* Bsm = smem + 2048;       // 128 x 64B bf16
    uint16_t* Ms = (uint16_t*)(smem + 10240);   // 128 x 18 u16 (pad)

    const int tid  = threadIdx.x;
    const int lane = tid & 63;
    const int w    = tid >> 6;                 // wave 0..3 -> j-group of 32
    const int quad = lane >> 4, l16 = lane & 15;
    const int i0   = blockIdx.x * 16;
    const int jw0  = w * 32;

    // ---- Phase 1: M1[i0..i0+16, :] = att[i0.., :] @ XW ----
    f32x4 acc1[2] = {(f32x4){0,0,0,0}, (f32x4){0,0,0,0}};
    for (int k0 = 0; k0 < NN; k0 += 32) {
        __syncthreads();
        if (tid < 64)
            gld_lds16(att + (size_t)(i0 + (tid >> 2)) * NN + k0 + (tid & 3) * 8, Asm + tid * 16);
        gld_lds16(XWT + (size_t)(tid >> 2) * NN + k0 + (tid & 3) * 8,        Bsm + tid * 16);
        gld_lds16(XWT + (size_t)(64 + (tid >> 2)) * NN + k0 + (tid & 3) * 8, Bsm + 4096 + tid * 16);
        __syncthreads();
        bf16x8 af = *(const bf16x8*)(Asm + l16 * 64 + quad * 16);
        #pragma unroll
        for (int n = 0; n < 2; ++n) {
            bf16x8 bf = *(const bf16x8*)(Bsm + (jw0 + n * 16 + l16) * 64 + quad * 16);
            acc1[n] = __builtin_amdgcn_mfma_f32_16x16x32_bf16(af, bf, acc1[n], 0, 0, 0);
        }
    }
    __syncthreads();
    // C/D: col = lane&15 (j), row = quad*4+reg (i-local). Transpose via LDS.
    #pragma unroll
    for (int n = 0; n < 2; ++n) {
        const int j = jw0 + n * 16 + l16;
        #pragma unroll
        for (int r = 0; r < 4; ++r)
            Ms[j * 18 + quad * 4 + r] = f2b(acc1[n][r]);
    }
    __syncthreads();
    {
        const int j = tid >> 1, part = tid & 1;
        *(u16x8*)(M1T + (size_t)j * NN + i0 + part * 8) = *(const u16x8*)(Ms + j * 18 + part * 8);
    }
    __threadfence();
    cg::this_grid().sync();

    // ---- Phase 2: H[i0..i0+16, :] = A[i0.., :] @ M1  (B^T = M1T) ----
    f32x4 acc2[2] = {(f32x4){0,0,0,0}, (f32x4){0,0,0,0}};
    for (int k0 = 0; k0 < NN; k0 += 32) {
        __syncthreads();
        if (tid < 128)
            gld_lds16(A + (size_t)(i0 + (tid >> 3)) * NN + k0 + (tid & 7) * 4, Asm + tid * 16);
        gld_lds16(M1T + (size_t)(tid >> 2) * NN + k0 + (tid & 3) * 8,        Bsm + tid * 16);
        gld_lds16(M1T + (size_t)(64 + (tid >> 2)) * NN + k0 + (tid & 3) * 8, Bsm + 4096 + tid * 16);
        __syncthreads();
        float4 a0 = *(const float4*)(Asm + l16 * 128 + quad * 32);
        float4 a1 = *(const float4*)(Asm + l16 * 128 + quad * 32 + 16);
        u16x8 au;
        au[0] = f2b(a0.x); au[1] = f2b(a0.y); au[2] = f2b(a0.z); au[3] = f2b(a0.w);
        au[4] = f2b(a1.x); au[5] = f2b(a1.y); au[6] = f2b(a1.z); au[7] = f2b(a1.w);
        bf16x8 af;
        __builtin_memcpy(&af, &au, 16);
        #pragma unroll
        for (int n = 0; n < 2; ++n) {
            bf16x8 bf = *(const bf16x8*)(Bsm + (jw0 + n * 16 + l16) * 64 + quad * 16);
            acc2[n] = __builtin_amdgcn_mfma_f32_16x16x32_bf16(af, bf, acc2[n], 0, 0, 0);
        }
    }
    #pragma unroll
    for (int n = 0; n < 2; ++n) {
        const int j = jw0 + n * 16 + l16;
        #pragma unroll
        for (int r = 0; r < 4; ++r)
            H[(size_t)(i0 + quad * 4 + r) * NF + j] = acc2[n][r];
    }
}

// ---------------------------------------------------------------------------
extern "C" void kernel_launch(void* const* d_in, const int* in_sizes, int n_in,
                              void* d_out, int out_size, void* d_ws, size_t ws_size,
                              hipStream_t stream) {
    (void)in_sizes; (void)n_in; (void)out_size; (void)ws_size;
    const float* X = (const float*)d_in[0];
    const float* A = (const float*)d_in[1];
    const float* W = (const float*)d_in[2];
    const float* a = (const float*)d_in[3];
    float* H = (float*)d_out;

    char* ws = (char*)d_ws;
    uint32_t* denT8 = (uint32_t*)(ws);                          // 16 MB fp8
    uint8_t*  Ab8   = (uint8_t*) (ws + ((size_t)16 << 20));     // 16 MB fp8
    uint16_t* att   = (uint16_t*)(ws + ((size_t)32 << 20));     // 32 MB bf16
    uint16_t* XWT   = (uint16_t*)(ws + ((size_t)64 << 20));     // 1 MB
    uint16_t* M1T   = (uint16_t*)(ws + ((size_t)65 << 20));     // 1 MB
    float*    s_col = (float*)   (ws + ((size_t)66 << 20));     // 16 KB
    float*    s_row = (float*)   (ws + ((size_t)66 << 20) + 16384);

    xw_kernel<<<NN, NF, 0, stream>>>(X, W, a, XWT, s_col, s_row);
    conv8_kernel<<<(NN * NN / 4) / 256, 256, 0, stream>>>(A, (uint32_t*)Ab8);
    denT_kernel<<<(NN * 1024) / 256, 256, 0, stream>>>(s_row, s_col, denT8);
    gemm_att_kernel<<<dim3(32, 32), 256, 0, stream>>>(Ab8, (const uint8_t*)denT8, s_row, s_col, att);

    void* args[] = {(void*)&att, (void*)&XWT, (void*)&A, (void*)&M1T, (void*)&H};
    hipLaunchCooperativeKernel((void*)tail_kernel, dim3(256), dim3(256), args, 0, stream);
}

// Round 6
// 324.515 us; speedup vs baseline: 1.2819x; 1.2819x over previous
//
#include <hip/hip_runtime.h>
#include <hip/hip_bf16.h>
#include <stdint.h>

#define NN 4096
#define NF 128

using f32x4  = __attribute__((ext_vector_type(4))) float;
using f32x16 = __attribute__((ext_vector_type(16))) float;
using bf16x8 = __attribute__((ext_vector_type(8))) __bf16;
using u16x8  = __attribute__((ext_vector_type(8))) uint16_t;
using i32x4  = __attribute__((ext_vector_type(4))) int;
using i32x8  = __attribute__((ext_vector_type(8))) int;

__device__ __forceinline__ uint16_t f2b(float f) {
    union { float f; uint32_t u; } v; v.f = f;
    uint32_t r = v.u + 0x7FFFu + ((v.u >> 16) & 1u);
    return (uint16_t)(r >> 16);
}

__device__ __forceinline__ uint32_t pk_fp8x4(float a, float b, float c, float d) {
    int p = __builtin_amdgcn_cvt_pk_fp8_f32(a, b, 0, false);
    p = __builtin_amdgcn_cvt_pk_fp8_f32(c, d, p, true);
    return (uint32_t)p;
}

__device__ __forceinline__ void gld_lds16(const void* g, void* l) {
    __builtin_amdgcn_global_load_lds(
        (const __attribute__((address_space(1))) uint32_t*)g,
        (__attribute__((address_space(3))) uint32_t*)l,
        16, 0, 0);
}

// ---------------------------------------------------------------------------
// Kernel 1: XW = X@W, s_col = XW@a[:128], s_row = XW@a[128:], XWT bf16
// ---------------------------------------------------------------------------
__global__ void xw_kernel(const float* __restrict__ X, const float* __restrict__ W,
                          const float* __restrict__ a,
                          uint16_t* __restrict__ XWT,
                          float* __restrict__ s_col, float* __restrict__ s_row) {
    __shared__ float xs[NF];
    __shared__ float red[4];
    const int i = blockIdx.x, f = threadIdx.x;
    xs[f] = X[i * NF + f];
    __syncthreads();
    float acc = 0.f;
    #pragma unroll 8
    for (int k = 0; k < NF; ++k) acc += xs[k] * W[k * NF + f];
    XWT[(size_t)f * NN + i] = f2b(acc);
    float sc = acc * a[f];
    float sr = acc * a[NF + f];
    #pragma unroll
    for (int off = 32; off; off >>= 1) {
        sc += __shfl_down(sc, off);
        sr += __shfl_down(sr, off);
    }
    if ((f & 63) == 0) { red[f >> 6] = sc; red[2 + (f >> 6)] = sr; }
    __syncthreads();
    if (f == 0) {
        s_col[i] = red[0] + red[1];
        s_row[i] = red[2] + red[3];
    }
}

// ---------------------------------------------------------------------------
// Kernel 2: A fp32 -> fp8-e4m3 (big GEMM operand)
// ---------------------------------------------------------------------------
__global__ void conv8_kernel(const float* __restrict__ in, uint32_t* __restrict__ o8) {
    int idx = blockIdx.x * blockDim.x + threadIdx.x;
    float4 v = ((const float4*)in)[idx];
    o8[idx] = pk_fp8x4(v.x, v.y, v.z, v.w);
}

// ---------------------------------------------------------------------------
// Kernel 3: denT8[j][k] = fp8(exp(leaky_relu(s_row[k] + s_col[j])))
// ---------------------------------------------------------------------------
__global__ void denT_kernel(const float* __restrict__ s_row, const float* __restrict__ s_col,
                            uint32_t* __restrict__ denT8) {
    int idx = blockIdx.x * blockDim.x + threadIdx.x;
    int j = idx >> 10;
    int k = (idx & 1023) << 2;
    float sc = s_col[j];
    float4 sr = *(const float4*)(s_row + k);
    float z0 = sc + sr.x; z0 = z0 > 0.f ? z0 : 0.01f * z0;
    float z1 = sc + sr.y; z1 = z1 > 0.f ? z1 : 0.01f * z1;
    float z2 = sc + sr.z; z2 = z2 > 0.f ? z2 : 0.01f * z2;
    float z3 = sc + sr.w; z3 = z3 > 0.f ? z3 : 0.01f * z3;
    denT8[idx] = pk_fp8x4(__expf(z0), __expf(z1), __expf(z2), __expf(z3));
}

// ---------------------------------------------------------------------------
// Kernel 4 (R3): num = A@den via MX-FP8 mfma_scale 32x32x64, fused att epilogue
// ---------------------------------------------------------------------------
__global__ __launch_bounds__(256) void gemm_att_kernel(
    const uint8_t* __restrict__ Ab8, const uint8_t* __restrict__ Bt8,
    const float* __restrict__ s_row, const float* __restrict__ s_col,
    uint16_t* __restrict__ att) {
    __shared__ __align__(16) char smem[128 * 272];
    char* As = smem;
    char* Bs = smem + 8192;
    const int bm0 = blockIdx.y * 128, bn0 = blockIdx.x * 128;

    const int tid  = threadIdx.x;
    const int lane = tid & 63;
    const int wid  = tid >> 6;
    const int wy   = wid >> 1, wx = wid & 1;
    const int m    = lane & 31, h = lane >> 5;

    const int sr_ = tid >> 2;
    const int scb = (((tid & 3) ^ ((sr_ >> 1) & 3)) << 4);

    f32x16 acc[2][2];
    #pragma unroll
    for (int mi = 0; mi < 2; ++mi)
        #pragma unroll
        for (int ni = 0; ni < 2; ++ni)
            #pragma unroll
            for (int r = 0; r < 16; ++r) acc[mi][ni][r] = 0.f;

    const int sw = (m >> 1) & 3;
    const int c0 = ((2 * h) ^ sw) << 4;
    const int c1 = ((2 * h + 1) ^ sw) << 4;

    for (int k0 = 0; k0 < NN; k0 += 64) {
        __syncthreads();
        gld_lds16(Ab8 + (size_t)(bm0 +      sr_) * NN + k0 + scb, As +        tid * 16);
        gld_lds16(Ab8 + (size_t)(bm0 + 64 + sr_) * NN + k0 + scb, As + 4096 + tid * 16);
        gld_lds16(Bt8 + (size_t)(bn0 +      sr_) * NN + k0 + scb, Bs +        tid * 16);
        gld_lds16(Bt8 + (size_t)(bn0 + 64 + sr_) * NN + k0 + scb, Bs + 4096 + tid * 16);
        __syncthreads();
        i32x8 af[2], bf[2];
        #pragma unroll
        for (int mi = 0; mi < 2; ++mi) {
            const char* p = As + (wy * 64 + mi * 32 + m) * 64;
            i32x4 lo = *(const i32x4*)(p + c0);
            i32x4 hi = *(const i32x4*)(p + c1);
            af[mi] = (i32x8){lo[0], lo[1], lo[2], lo[3], hi[0], hi[1], hi[2], hi[3]};
        }
        #pragma unroll
        for (int ni = 0; ni < 2; ++ni) {
            const char* p = Bs + (wx * 64 + ni * 32 + m) * 64;
            i32x4 lo = *(const i32x4*)(p + c0);
            i32x4 hi = *(const i32x4*)(p + c1);
            bf[ni] = (i32x8){lo[0], lo[1], lo[2], lo[3], hi[0], hi[1], hi[2], hi[3]};
        }
        #pragma unroll
        for (int mi = 0; mi < 2; ++mi)
            #pragma unroll
            for (int ni = 0; ni < 2; ++ni)
                acc[mi][ni] = __builtin_amdgcn_mfma_scale_f32_32x32x64_f8f6f4(
                    af[mi], bf[ni], acc[mi][ni], 0, 0,
                    0, 0x7F7F7F7F, 0, 0x7F7F7F7F);
    }

    __syncthreads();
    uint16_t* smem16 = (uint16_t*)smem;

    #pragma unroll
    for (int ni = 0; ni < 2; ++ni) {
        const int jl = wx * 64 + ni * 32 + m;
        const float scj = s_col[bn0 + jl];
        #pragma unroll
        for (int mi = 0; mi < 2; ++mi) {
            #pragma unroll
            for (int reg = 0; reg < 16; ++reg) {
                const int row = (reg & 3) + 8 * (reg >> 2) + 4 * h;
                const int il = wy * 64 + mi * 32 + row;
                float z = s_row[bm0 + il] + scj;
                z = z > 0.f ? z : 0.01f * z;
                const float den = __expf(z);
                const float num = acc[mi][ni][reg];
                float v = den * __builtin_amdgcn_rcpf(num);
                v = (num != 0.f) ? v : 0.f;
                smem16[il * 136 + jl] = f2b(v);
            }
        }
    }
    __syncthreads();
    {
        const int row = tid >> 1, half = tid & 1;
        const u16x8* src = (const u16x8*)(smem16 + row * 136 + half * 64);
        u16x8* dst = (u16x8*)(att + (size_t)(bm0 + row) * NN + bn0 + half * 64);
        #pragma unroll
        for (int c = 0; c < 8; ++c) dst[c] = src[c];
    }
}

// ---------------------------------------------------------------------------
// Kernel 5: wave-level GEMM, phase 1: P1[z][f][i] = sum_{k in chunk}
// XWT[f][k]*att[i][k]   (computes M1^T so all stores are coalesced).
// No LDS, no barriers — each wave owns a 16f x 32i tile + K-chunk of 1024.
// Grid (128 i-tiles, 2 f-halves, 4 k-splits); 4 waves/block share att reads.
// ---------------------------------------------------------------------------
__global__ __launch_bounds__(256) void wg1_kernel(
    const uint16_t* __restrict__ XWT, const uint16_t* __restrict__ att,
    float* __restrict__ P1) {
    const int tid = threadIdx.x, lane = tid & 63, w = tid >> 6;
    const int quad = lane >> 4, l16 = lane & 15;
    const int i0 = blockIdx.x * 32;
    const int f0 = blockIdx.y * 64 + w * 16;
    const int z  = blockIdx.z;
    const int kBeg = z * (NN / 4);

    const uint16_t* pa  = XWT + (size_t)(f0 + l16)      * NN + quad * 8 + kBeg;
    const uint16_t* pb0 = att + (size_t)(i0 + l16)      * NN + quad * 8 + kBeg;
    const uint16_t* pb1 = att + (size_t)(i0 + 16 + l16) * NN + quad * 8 + kBeg;

    f32x4 acc[2] = {(f32x4){0,0,0,0}, (f32x4){0,0,0,0}};
    #pragma unroll 4
    for (int k = 0; k < NN / 4; k += 32) {
        bf16x8 af = *(const bf16x8*)(pa  + k);
        bf16x8 b0 = *(const bf16x8*)(pb0 + k);
        bf16x8 b1 = *(const bf16x8*)(pb1 + k);
        acc[0] = __builtin_amdgcn_mfma_f32_16x16x32_bf16(af, b0, acc[0], 0, 0, 0);
        acc[1] = __builtin_amdgcn_mfma_f32_16x16x32_bf16(af, b1, acc[1], 0, 0, 0);
    }
    float* Pp = P1 + (size_t)z * (NF * NN);
    #pragma unroll
    for (int ni = 0; ni < 2; ++ni)
        #pragma unroll
        for (int r = 0; r < 4; ++r)
            Pp[(size_t)(f0 + quad * 4 + r) * NN + i0 + ni * 16 + l16] = acc[ni][r];
}

// ---------------------------------------------------------------------------
// Kernel 6: M1T[f][i] = bf16(sum_z P1[z][f][i])  — fully coalesced both sides
// ---------------------------------------------------------------------------
__global__ void reduce1_kernel(const float* __restrict__ P1, uint16_t* __restrict__ M1T) {
    int idx = blockIdx.x * 256 + threadIdx.x;
    float s = 0.f;
    #pragma unroll
    for (int z = 0; z < 4; ++z) s += P1[(size_t)z * (NF * NN) + idx];
    M1T[idx] = f2b(s);
}

// ---------------------------------------------------------------------------
// Kernel 7: wave-level GEMM, phase 2: P2[z][i][f] = sum_{k chunk} A[i][k]*M1T[f][k]
// A loaded fp32 directly, converted in-register. Grid (256 i-tiles, 4 k-splits);
// 4 waves/block cover all 128 f and share A reads (L1).
// ---------------------------------------------------------------------------
__global__ __launch_bounds__(256) void wg2_kernel(
    const float* __restrict__ A, const uint16_t* __restrict__ M1T,
    float* __restrict__ P2) {
    const int tid = threadIdx.x, lane = tid & 63, w = tid >> 6;
    const int quad = lane >> 4, l16 = lane & 15;
    const int i0 = blockIdx.x * 16;
    const int f0 = w * 32;
    const int z  = blockIdx.y;
    const int kBeg = z * (NN / 4);

    const float*    pa  = A   + (size_t)(i0 + l16)      * NN + quad * 8 + kBeg;
    const uint16_t* pb0 = M1T + (size_t)(f0 + l16)      * NN + quad * 8 + kBeg;
    const uint16_t* pb1 = M1T + (size_t)(f0 + 16 + l16) * NN + quad * 8 + kBeg;

    f32x4 acc[2] = {(f32x4){0,0,0,0}, (f32x4){0,0,0,0}};
    #pragma unroll 4
    for (int k = 0; k < NN / 4; k += 32) {
        float4 a0 = *(const float4*)(pa + k);
        float4 a1 = *(const float4*)(pa + k + 4);
        u16x8 au;
        au[0] = f2b(a0.x); au[1] = f2b(a0.y); au[2] = f2b(a0.z); au[3] = f2b(a0.w);
        au[4] = f2b(a1.x); au[5] = f2b(a1.y); au[6] = f2b(a1.z); au[7] = f2b(a1.w);
        bf16x8 af;
        __builtin_memcpy(&af, &au, 16);
        bf16x8 b0 = *(const bf16x8*)(pb0 + k);
        bf16x8 b1 = *(const bf16x8*)(pb1 + k);
        acc[0] = __builtin_amdgcn_mfma_f32_16x16x32_bf16(af, b0, acc[0], 0, 0, 0);
        acc[1] = __builtin_amdgcn_mfma_f32_16x16x32_bf16(af, b1, acc[1], 0, 0, 0);
    }
    float* Pp = P2 + (size_t)z * (NN * NF);
    #pragma unroll
    for (int ni = 0; ni < 2; ++ni)
        #pragma unroll
        for (int r = 0; r < 4; ++r)
            Pp[(size_t)(i0 + quad * 4 + r) * NF + f0 + ni * 16 + l16] = acc[ni][r];
}

// ---------------------------------------------------------------------------
// Kernel 8: H[i][f] = sum_z P2[z][i][f]  — fully coalesced
// ---------------------------------------------------------------------------
__global__ void reduce2_kernel(const float* __restrict__ P2, float* __restrict__ out) {
    int idx = blockIdx.x * 256 + threadIdx.x;
    float s = 0.f;
    #pragma unroll
    for (int z = 0; z < 4; ++z) s += P2[(size_t)z * (NN * NF) + idx];
    out[idx] = s;
}

// ---------------------------------------------------------------------------
extern "C" void kernel_launch(void* const* d_in, const int* in_sizes, int n_in,
                              void* d_out, int out_size, void* d_ws, size_t ws_size,
                              hipStream_t stream) {
    (void)in_sizes; (void)n_in; (void)out_size; (void)ws_size;
    const float* X = (const float*)d_in[0];
    const float* A = (const float*)d_in[1];
    const float* W = (const float*)d_in[2];
    const float* a = (const float*)d_in[3];
    float* H = (float*)d_out;

    char* ws = (char*)d_ws;
    uint32_t* denT8 = (uint32_t*)(ws);                          // 16 MB fp8
    uint8_t*  Ab8   = (uint8_t*) (ws + ((size_t)16 << 20));     // 16 MB fp8
    uint16_t* att   = (uint16_t*)(ws + ((size_t)32 << 20));     // 32 MB bf16
    uint16_t* XWT   = (uint16_t*)(ws + ((size_t)64 << 20));     // 1 MB
    uint16_t* M1T   = (uint16_t*)(ws + ((size_t)65 << 20));     // 1 MB
    float*    s_col = (float*)   (ws + ((size_t)66 << 20));     // 16 KB
    float*    s_row = (float*)   (ws + ((size_t)66 << 20) + 16384);
    float*    P     = (float*)   (ws + ((size_t)67 << 20));     // 8 MB (P1 then P2)

    xw_kernel<<<NN, NF, 0, stream>>>(X, W, a, XWT, s_col, s_row);
    conv8_kernel<<<(NN * NN / 4) / 256, 256, 0, stream>>>(A, (uint32_t*)Ab8);
    denT_kernel<<<(NN * 1024) / 256, 256, 0, stream>>>(s_row, s_col, denT8);
    gemm_att_kernel<<<dim3(32, 32), 256, 0, stream>>>(Ab8, (const uint8_t*)denT8, s_row, s_col, att);
    wg1_kernel<<<dim3(128, 2, 4), 256, 0, stream>>>(XWT, att, P);
    reduce1_kernel<<<(NF * NN) / 256, 256, 0, stream>>>(P, M1T);
    wg2_kernel<<<dim3(256, 4), 256, 0, stream>>>(A, M1T, P);
    reduce2_kernel<<<(NN * NF) / 256, 256, 0, stream>>>(P, H);
}